// Round 12
// baseline (261.589 us; speedup 1.0000x reference)
//
#include <hip/hip_runtime.h>

// LowRankRotatedSpaceIntervention — v12: ring-3 + 12 waves/CU (in-flight/CU).
// out[b,:] = base[b,:] + (mask_b . ((source[b,:]-base[b,:]) @ W)) @ W^T
// B=16384, D=4096, R=64, 8 partitions of 8, 4 selected per row.
//
// R1-R11 model: effective HBM latency under load ~3-4us (queued); BW is
// proportional to outstanding data bytes per CU. All prior variants held
// <=2 chunks/wave and <=8 waves/CU (~40-50 KB/CU) => ~2.8 TB/s plateau.
// v12 raises in-flight ~2.3x: ring-3 LDS staging (2 chunks ahead always) x
// 12 waves/CU (LDS 50 KB/block => 3 blocks/CU). W fragments in registers
// via v7's order-pinned asm (ring-3 wbA/B/C) so the vmcnt ledger is exact:
// 8 ops/chunk, VMWAIT(16) in steady state drains exactly chunk c.

#define D_DIM 4096
#define R_DIM 64
#define BM    16
#define NCHK  32               // 32-col chunks per 1024-col wave quarter
#define SLOT  4096             // ring slot: 2KB base + 2KB src
#define WREG  12288            // wave region = 3 slots
#define OFF_RM      49152      // [16][72] bf16 = 2304 B
#define SMEM_BYTES  51456      // -> 3 blocks/CU

typedef short bf16vec8 __attribute__((ext_vector_type(8)));
typedef float f32x4v  __attribute__((ext_vector_type(4)));
typedef unsigned int u32x4 __attribute__((ext_vector_type(4)));

#define VMWAIT(N)                                              \
  do {                                                         \
    asm volatile("s_waitcnt vmcnt(" #N ")" ::: "memory");      \
    __builtin_amdgcn_sched_barrier(0);                         \
  } while (0)

__device__ __forceinline__ unsigned int f2bf_u(float f) {
  unsigned int u = __builtin_bit_cast(unsigned int, f);
  return (u + 0x7fffu + ((u >> 16) & 1u)) >> 16;   // RNE
}
__device__ __forceinline__ unsigned int pack2bf(float a, float b) {
  return f2bf_u(a) | (f2bf_u(b) << 16);
}
__device__ __forceinline__ void async_ld16(const void* g, void* l) {
  __builtin_amdgcn_global_load_lds(
      (const __attribute__((address_space(1))) void*)g,
      (__attribute__((address_space(3))) void*)l, 16, 0, 0);
}

__global__ __launch_bounds__(256)
void lrri_prep(const float* __restrict__ W, unsigned short* __restrict__ Wt,
               unsigned short* __restrict__ Wb) {
  const int idx = blockIdx.x * blockDim.x + threadIdx.x;   // 0..65535
  const int k = idx >> 4;
  const int j = (idx & 15) * 4;
  float4 w = *(const float4*)(W + (size_t)k * R_DIM + j);
  ushort4 p;
  p.x = (unsigned short)f2bf_u(w.x);
  p.y = (unsigned short)f2bf_u(w.y);
  p.z = (unsigned short)f2bf_u(w.z);
  p.w = (unsigned short)f2bf_u(w.w);
  *(ushort4*)(Wb + (size_t)k * R_DIM + j) = p;     // [4096][64] bf16
  Wt[(size_t)(j + 0) * D_DIM + k] = p.x;           // [64][4096] bf16
  Wt[(size_t)(j + 1) * D_DIM + k] = p.y;
  Wt[(size_t)(j + 2) * D_DIM + k] = p.z;
  Wt[(size_t)(j + 3) * D_DIM + k] = p.w;
}

template<bool USE_WS>
__global__ __launch_bounds__(256, 3)
void lrri_fused(const float* __restrict__ base, const float* __restrict__ srcp,
                const float* __restrict__ W, const int* __restrict__ subs,
                const unsigned short* __restrict__ Wt_bf,   // [64][4096]
                const unsigned short* __restrict__ Wb_bf,   // [4096][64]
                float* __restrict__ out)
{
  __shared__ __align__(16) unsigned char smem[SMEM_BYTES];
  const int tid  = threadIdx.x;
  const int wave = tid >> 6;             // K-quarter owner
  const int lane = tid & 63;
  const int l4   = lane & 15;
  const int g    = lane >> 4;
  const long rowbase = (long)blockIdx.x * BM;
  unsigned char* region = smem + wave * WREG;
  const int kq0  = wave * 1024;
  const int off1 = (blockIdx.x * 7) & 31;
  const int off2 = (blockIdx.x * 5) & 15;

  // stage chunk c into slot c%3: 16 rows x 128B of base and src (4 gload_lds)
  auto stage = [&](int c) {
    unsigned char* buf = region + (c % 3) * SLOT;
    const int ch = (c + off1) & 31;
    const long colf = kq0 + ch * 32;
    #pragma unroll
    for (int q = 0; q < 2; ++q) {
      const int r = q * 8 + (lane >> 3);
      const unsigned b = ((unsigned)((lane & 7) * 16)) ^ ((unsigned)((r & 7) << 4));
      const long goff = (rowbase + r) * (long)D_DIM + colf + (b >> 2);
      async_ld16(base + goff, buf + q * 1024);
    }
    #pragma unroll
    for (int q = 0; q < 2; ++q) {
      const int r = q * 8 + (lane >> 3);
      const unsigned b = ((unsigned)((lane & 7) * 16)) ^ ((unsigned)((r & 7) << 4));
      const long goff = (rowbase + r) * (long)D_DIM + colf + (b >> 2);
      async_ld16(srcp + goff, buf + 2048 + q * 1024);
    }
  };

  // 4 order-pinned W-fragment loads (one per j-tile t) for chunk c.
  auto wload = [&](u32x4 (&dst)[4], int c) {
    const int ch = (c + off1) & 31;
    const long colf = kq0 + ch * 32;
    const char* wbp = (const char*)Wt_bf + (size_t)l4 * 8192 + colf * 2 + g * 16;
    const char* a0 = wbp;
    const char* a1 = wbp + 1 * 131072;
    const char* a2 = wbp + 2 * 131072;
    const char* a3 = wbp + 3 * 131072;
    asm volatile(
        "global_load_dwordx4 %0, %4, off\n\t"
        "global_load_dwordx4 %1, %5, off\n\t"
        "global_load_dwordx4 %2, %6, off\n\t"
        "global_load_dwordx4 %3, %7, off"
        : "=&v"(dst[0]), "=&v"(dst[1]), "=&v"(dst[2]), "=&v"(dst[3])
        : "v"(a0), "v"(a1), "v"(a2), "v"(a3)
        : "memory");
  };

  f32x4v acc[4];
  #pragma unroll
  for (int t = 0; t < 4; ++t) acc[t] = (f32x4v){0.f, 0.f, 0.f, 0.f};

  auto compute = [&](int c, const u32x4 (&wf)[4]) {
    const unsigned char* buf = region + (c % 3) * SLOT;
    const unsigned sw = (unsigned)((l4 & 7) << 4);
    const unsigned c0 = ((unsigned)(g * 32)) ^ sw;
    const unsigned c1 = ((unsigned)(g * 32 + 16)) ^ sw;
    float4 fb0 = *(const float4*)(buf + l4 * 128 + c0);
    float4 fb1 = *(const float4*)(buf + l4 * 128 + c1);
    float4 fs0 = *(const float4*)(buf + 2048 + l4 * 128 + c0);
    float4 fs1 = *(const float4*)(buf + 2048 + l4 * 128 + c1);
    u32x4 af;
    af[0] = pack2bf(fs0.x - fb0.x, fs0.y - fb0.y);
    af[1] = pack2bf(fs0.z - fb0.z, fs0.w - fb0.w);
    af[2] = pack2bf(fs1.x - fb1.x, fs1.y - fb1.y);
    af[3] = pack2bf(fs1.z - fb1.z, fs1.w - fb1.w);
    #pragma unroll
    for (int t = 0; t < 4; ++t)
      acc[t] = __builtin_amdgcn_mfma_f32_16x16x32_bf16(
          __builtin_bit_cast(bf16vec8, af),
          __builtin_bit_cast(bf16vec8, wf[t]), acc[t], 0, 0, 0);
  };

  // ---------------- Phase 1 -----------------------------------------------
  if constexpr (USE_WS) {
    u32x4 wbA[4], wbB[4], wbC[4];
    stage(0); wload(wbA, 0);
    stage(1); wload(wbB, 1);
    stage(2); wload(wbC, 2);            // queue: 24 ops (chunks 0,1,2)
    #pragma unroll 1
    for (int c = 0; c < 27; c += 3) {
      VMWAIT(16); compute(c,     wbA); stage(c + 3); wload(wbA, c + 3);
      VMWAIT(16); compute(c + 1, wbB); stage(c + 4); wload(wbB, c + 4);
      VMWAIT(16); compute(c + 2, wbC); stage(c + 5); wload(wbC, c + 5);
    }
    VMWAIT(16); compute(27, wbA); stage(30); wload(wbA, 30);
    VMWAIT(16); compute(28, wbB); stage(31); wload(wbB, 31);
    VMWAIT(16); compute(29, wbC);
    VMWAIT(8);  compute(30, wbA);
    VMWAIT(0);  compute(31, wbB);
  } else {
    // fallback: serial full-drain; W from fp32 global via compiler loads
    #pragma unroll 1
    for (int c = 0; c < NCHK; ++c) {
      stage(c);
      VMWAIT(0);
      const int ch = (c + off1) & 31;
      const long colf = kq0 + ch * 32;
      u32x4 wf[4];
      #pragma unroll
      for (int t = 0; t < 4; ++t) {
        unsigned int pq[4];
        #pragma unroll
        for (int e2 = 0; e2 < 4; ++e2) {
          float wa = W[(size_t)(colf + g * 8 + e2 * 2    ) * R_DIM + t * 16 + l4];
          float wb = W[(size_t)(colf + g * 8 + e2 * 2 + 1) * R_DIM + t * 16 + l4];
          pq[e2] = pack2bf(wa, wb);
        }
        wf[t][0] = pq[0]; wf[t][1] = pq[1]; wf[t][2] = pq[2]; wf[t][3] = pq[3];
      }
      compute(c, wf);
    }
  }

  // per-wave K-quarter partials -> own region (ring drained): [16][72] f32
  {
    float* part = (float*)region;
    #pragma unroll
    for (int t = 0; t < 4; ++t)
      #pragma unroll
      for (int i = 0; i < 4; ++i)
        part[(g * 4 + i) * 72 + t * 16 + l4] = acc[t][i];
  }
  __syncthreads();

  // ---------------- Reduce K-quarters + per-row partition mask ------------
  {
    const int row = tid >> 4, jg = tid & 15;
    const float* p0 = (const float*)smem;           // wave w at w*3072 floats
    int4 sb = *(const int4*)(subs + (rowbase + row) * 4);
    unsigned mbits = (1u << sb.x) | (1u << sb.y) | (1u << sb.z) | (1u << sb.w);
    unsigned short vals[4];
    #pragma unroll
    for (int jj = 0; jj < 4; ++jj) {
      const int j = jg * 4 + jj;
      float sum = p0[row * 72 + j] + p0[3072 + row * 72 + j] +
                  p0[6144 + row * 72 + j] + p0[9216 + row * 72 + j];
      vals[jj] = ((mbits >> (j >> 3)) & 1u) ? (unsigned short)f2bf_u(sum)
                                            : (unsigned short)0;
    }
    unsigned short* rm = (unsigned short*)(smem + OFF_RM);
    uint2 pk;
    pk.x = (unsigned)vals[0] | ((unsigned)vals[1] << 16);
    pk.y = (unsigned)vals[2] | ((unsigned)vals[3] << 16);
    *(uint2*)(rm + row * 72 + jg * 4) = pk;
  }
  __syncthreads();

  // ---------------- Phase 2: out = base(global) + rm @ W^T ----------------
  uint4 a2[2];
  #pragma unroll
  for (int s = 0; s < 2; ++s)
    a2[s] = *(const uint4*)(smem + OFF_RM + l4 * 144 + s * 64 + g * 16);
  float* cbuf = (float*)region;        // [16][72] f32, wave-private
  #pragma unroll 1
  for (int grp = 0; grp < 16; ++grp) {
    const int ga = (grp + off2) & 15;
    const int cbase = kq0 + ga * 64;
    float4 bb[4];
    #pragma unroll
    for (int i2 = 0; i2 < 4; ++i2) {
      const int r = g + i2 * 4;
      bb[i2] = *(const float4*)(base + (rowbase + r) * (long)D_DIM + cbase + l4 * 4);
    }
    f32x4v a[4];
    #pragma unroll
    for (int t = 0; t < 4; ++t) a[t] = (f32x4v){0.f, 0.f, 0.f, 0.f};
    #pragma unroll
    for (int t = 0; t < 4; ++t) {
      #pragma unroll
      for (int s = 0; s < 2; ++s) {
        uint4 bfrag;  // B[kk=j][n=col] = W[col][j]
        if (USE_WS) {
          bfrag = *(const uint4*)(Wb_bf + (size_t)(cbase + t * 16 + l4) * R_DIM +
                                  s * 32 + g * 8);
        } else {
          const float* wp = W + (size_t)(cbase + t * 16 + l4) * R_DIM + s * 32 + g * 8;
          float4 wa = *(const float4*)(wp);
          float4 wc = *(const float4*)(wp + 4);
          bfrag.x = pack2bf(wa.x, wa.y); bfrag.y = pack2bf(wa.z, wa.w);
          bfrag.z = pack2bf(wc.x, wc.y); bfrag.w = pack2bf(wc.z, wc.w);
        }
        a[t] = __builtin_amdgcn_mfma_f32_16x16x32_bf16(
            __builtin_bit_cast(bf16vec8, a2[s]),
            __builtin_bit_cast(bf16vec8, bfrag), a[t], 0, 0, 0);
      }
    }
    #pragma unroll
    for (int t = 0; t < 4; ++t)
      #pragma unroll
      for (int i = 0; i < 4; ++i)
        cbuf[(g * 4 + i) * 72 + t * 16 + l4] = a[t][i];
    // transpose via wave-local LDS -> coalesced float4 stores
    #pragma unroll
    for (int i2 = 0; i2 < 4; ++i2) {
      const int r = g + i2 * 4;
      f32x4v cv = *(const f32x4v*)(cbuf + r * 72 + l4 * 4);
      float4 o;
      o.x = cv[0] + bb[i2].x;
      o.y = cv[1] + bb[i2].y;
      o.z = cv[2] + bb[i2].z;
      o.w = cv[3] + bb[i2].w;
      *(float4*)(out + (rowbase + r) * (long)D_DIM + cbase + l4 * 4) = o;
    }
  }
}

extern "C" void kernel_launch(void* const* d_in, const int* in_sizes, int n_in,
                              void* d_out, int out_size, void* d_ws, size_t ws_size,
                              hipStream_t stream) {
  const float* base = (const float*)d_in[0];
  const float* srcp = (const float*)d_in[1];
  const float* W    = (const float*)d_in[2];
  const int*   subs = (const int*)d_in[3];
  float* out = (float*)d_out;

  const int nblocks = 16384 / BM;   // 1024
  const size_t wbytes = (size_t)2 * R_DIM * D_DIM * sizeof(unsigned short); // 1 MB
  if (d_ws && ws_size >= wbytes) {
    unsigned short* Wt = (unsigned short*)d_ws;          // [64][4096] bf16
    unsigned short* Wb = Wt + (size_t)R_DIM * D_DIM;     // [4096][64] bf16
    lrri_prep<<<256, 256, 0, stream>>>(W, Wt, Wb);
    lrri_fused<true><<<nblocks, 256, 0, stream>>>(base, srcp, W, subs, Wt, Wb, out);
  } else {
    lrri_fused<false><<<nblocks, 256, 0, stream>>>(base, srcp, W, subs, nullptr, nullptr, out);
  }
}

// Round 13
// 228.158 us; speedup vs baseline: 1.1465x; 1.1465x over previous
//
#include <hip/hip_runtime.h>

// LowRankRotatedSpaceIntervention — v13 = v11 + XCD-aware bijective tile remap.
// out[b,:] = base[b,:] + (mask_b . ((source[b,:]-base[b,:]) @ W)) @ W^T
// B=16384, D=4096, R=64, 8 partitions of 8, 4 selected per row.
//
// R12 falsified the in-flight-bytes model (ring-3 x 12 waves/CU REGRESSED).
// Cross-round signal: BW is monotone in rows-per-block (BM 4/8/16/32 ->
// 1.0/1.8/2.3/2.9 TB/s) => per-block footprint locality, not pipeline depth,
// governs BW. v13 applies T1 (guide §5.5): 512 blocks = 8 XCDs x 64; remap
// tile=(b&7)*64+(b>>3) so each XCD's blocks stream one contiguous 32MB
// region per array (8 super-streams chip-wide instead of 512 interleaved).
// Stagger keyed to tile. Otherwise byte-identical to v11 (227.6 us best).

#define D_DIM 4096
#define R_DIM 64
#define BM    32
#define WAVESTG 16384            // per-wave: 2 chunk-slots x 8KB
#define OFF_RM  65536            // [32][72] bf16 = 4608 B
#define SMEM_BYTES 70144         // 2 blocks/CU

typedef short bf16vec8 __attribute__((ext_vector_type(8)));
typedef float f32x4v  __attribute__((ext_vector_type(4)));

#define VMWAIT(N)                                              \
  do {                                                         \
    asm volatile("s_waitcnt vmcnt(" #N ")" ::: "memory");      \
    __builtin_amdgcn_sched_barrier(0);                         \
  } while (0)

__device__ __forceinline__ unsigned int f2bf_u(float f) {
  unsigned int u = __builtin_bit_cast(unsigned int, f);
  return (u + 0x7fffu + ((u >> 16) & 1u)) >> 16;   // RNE
}
__device__ __forceinline__ unsigned int pack2bf(float a, float b) {
  return f2bf_u(a) | (f2bf_u(b) << 16);
}
__device__ __forceinline__ void async_ld16(const void* g, void* l) {
  __builtin_amdgcn_global_load_lds(
      (const __attribute__((address_space(1))) void*)g,
      (__attribute__((address_space(3))) void*)l, 16, 0, 0);
}

__global__ __launch_bounds__(256)
void lrri_prep(const float* __restrict__ W, unsigned short* __restrict__ Wt,
               unsigned short* __restrict__ Wb) {
  const int idx = blockIdx.x * blockDim.x + threadIdx.x;   // 0..65535
  const int k = idx >> 4;
  const int j = (idx & 15) * 4;
  float4 w = *(const float4*)(W + (size_t)k * R_DIM + j);
  ushort4 p;
  p.x = (unsigned short)f2bf_u(w.x);
  p.y = (unsigned short)f2bf_u(w.y);
  p.z = (unsigned short)f2bf_u(w.z);
  p.w = (unsigned short)f2bf_u(w.w);
  *(ushort4*)(Wb + (size_t)k * R_DIM + j) = p;     // [4096][64] bf16
  Wt[(size_t)(j + 0) * D_DIM + k] = p.x;           // [64][4096] bf16
  Wt[(size_t)(j + 1) * D_DIM + k] = p.y;
  Wt[(size_t)(j + 2) * D_DIM + k] = p.z;
  Wt[(size_t)(j + 3) * D_DIM + k] = p.w;
}

template<bool USE_WS>
__global__ __launch_bounds__(256, 2)
void lrri_fused(const float* __restrict__ base, const float* __restrict__ srcp,
                const float* __restrict__ W, const int* __restrict__ subs,
                const unsigned short* __restrict__ Wt_bf,   // [64][4096]
                const unsigned short* __restrict__ Wb_bf,   // [4096][64]
                float* __restrict__ out)
{
  __shared__ __align__(16) unsigned char smem[SMEM_BYTES];
  const int tid  = threadIdx.x;
  const int wave = tid >> 6;
  const int lane = tid & 63;
  const int l4   = lane & 15;
  const int g    = lane >> 4;
  const int rh   = wave >> 1;            // row-half: 16 rows
  const int kh   = wave & 1;             // K-half: 2048 cols
  // T1: XCD-aware bijective remap. 512 blocks = 8 XCDs x 64; dispatch
  // round-robins blockIdx%8 across XCDs, so give XCD x tiles [x*64,(x+1)*64).
  const int tile = (blockIdx.x & 7) * 64 + (blockIdx.x >> 3);
  const long rowbase = (long)tile * BM;
  const long rowg    = rowbase + rh * 16;
  unsigned char* wbuf = smem + wave * WAVESTG;
  const int off1 = (tile * 7) & 63;   // phase-1 chunk stagger (per tile)
  const int off2 = (tile * 5) & 15;   // phase-2 group stagger

  // ---------------- Phase 1: r = (src-base) @ W over this wave's K half ---
  // chunk = 32 cols. Slot layout (8KB): [0,2KB) base [16r][128B],
  // [2KB,4KB) src, [4KB,8KB) W slice [64j][64B]. All XOR-swizzled at source.
  f32x4v acc[4];
  #pragma unroll
  for (int t = 0; t < 4; ++t) acc[t] = (f32x4v){0.f, 0.f, 0.f, 0.f};

  auto stage = [&](int c) {                       // 8 gload_lds, order-pinned
    const int ch = (c + off1) & 63;               // rotated chunk id
    unsigned char* buf = wbuf + (c & 1) * 8192;
    const long colf = kh * 2048 + ch * 32;        // first float col
    #pragma unroll
    for (int q = 0; q < 2; ++q) {
      const int r = q * 8 + (lane >> 3);          // row_local
      const unsigned b = ((unsigned)((lane & 7) * 16)) ^ ((unsigned)(r & 7) << 4);
      const long goff = (rowg + r) * (long)D_DIM + colf + (b >> 2);
      async_ld16(base + goff, buf + q * 1024);
    }
    #pragma unroll
    for (int q = 0; q < 2; ++q) {
      const int r = q * 8 + (lane >> 3);
      const unsigned b = ((unsigned)((lane & 7) * 16)) ^ ((unsigned)(r & 7) << 4);
      const long goff = (rowg + r) * (long)D_DIM + colf + (b >> 2);
      async_ld16(srcp + goff, buf + 2048 + q * 1024);
    }
    // W slice [64j][32k bf16 = 64B]: 4 instrs; instr q covers j-rows 16q..+15
    #pragma unroll
    for (int q = 0; q < 4; ++q) {
      const int j = q * 16 + (lane >> 2);
      const unsigned kb = ((unsigned)((lane & 3) * 16)) ^ ((unsigned)(j & 3) << 4);
      const char* src = (const char*)Wt_bf + (size_t)j * (D_DIM * 2) +
                        colf * 2 + kb;
      async_ld16(src, buf + 4096 + q * 1024);
    }
  };

  auto compute = [&](int c) {
    const unsigned char* buf = wbuf + (c & 1) * 8192;
    const unsigned sw = (unsigned)((l4 & 7) << 4);
    const unsigned c0 = ((unsigned)(g * 32)) ^ sw;
    const unsigned c1 = ((unsigned)(g * 32 + 16)) ^ sw;
    float4 fb0 = *(const float4*)(buf + l4 * 128 + c0);
    float4 fb1 = *(const float4*)(buf + l4 * 128 + c1);
    float4 fs0 = *(const float4*)(buf + 2048 + l4 * 128 + c0);
    float4 fs1 = *(const float4*)(buf + 2048 + l4 * 128 + c1);
    uint4 af;
    af.x = pack2bf(fs0.x - fb0.x, fs0.y - fb0.y);
    af.y = pack2bf(fs0.z - fb0.z, fs0.w - fb0.w);
    af.z = pack2bf(fs1.x - fb1.x, fs1.y - fb1.y);
    af.w = pack2bf(fs1.z - fb1.z, fs1.w - fb1.w);
    const unsigned wsl = ((unsigned)(g * 16)) ^ ((unsigned)(l4 & 3) << 4);
    #pragma unroll
    for (int t = 0; t < 4; ++t) {
      uint4 wf = *(const uint4*)(buf + 4096 + (t * 16 + l4) * 64 + wsl);
      acc[t] = __builtin_amdgcn_mfma_f32_16x16x32_bf16(
          __builtin_bit_cast(bf16vec8, af),
          __builtin_bit_cast(bf16vec8, wf), acc[t], 0, 0, 0);
    }
  };

  if constexpr (USE_WS) {
    stage(0); stage(1);                 // queue: 16
    #pragma unroll 1
    for (int c = 0; c < 62; ++c) {
      VMWAIT(8);                        // drains chunk c exactly
      compute(c);                       // MFMA lgkm-dep proves ds_reads done
      __builtin_amdgcn_sched_barrier(0);
      stage(c + 2);                     // refill slot (c&1)
    }
    VMWAIT(8);
    compute(62);
    VMWAIT(0);
    compute(63);
  } else {
    // fallback: serial full-drain; W from fp32 global via registers
    #pragma unroll 1
    for (int c = 0; c < 64; ++c) {
      const int ch = (c + off1) & 63;
      unsigned char* buf = wbuf + (c & 1) * 8192;
      const long colf = kh * 2048 + ch * 32;
      #pragma unroll
      for (int q = 0; q < 2; ++q) {
        const int r = q * 8 + (lane >> 3);
        const unsigned b = ((unsigned)((lane & 7) * 16)) ^ ((unsigned)(r & 7) << 4);
        const long goff = (rowg + r) * (long)D_DIM + colf + (b >> 2);
        async_ld16(base + goff, buf + q * 1024);
        async_ld16(srcp + goff, buf + 2048 + q * 1024);
      }
      VMWAIT(0);
      const unsigned sw = (unsigned)((l4 & 7) << 4);
      const unsigned c0 = ((unsigned)(g * 32)) ^ sw;
      const unsigned c1 = ((unsigned)(g * 32 + 16)) ^ sw;
      float4 fb0 = *(const float4*)(buf + l4 * 128 + c0);
      float4 fb1 = *(const float4*)(buf + l4 * 128 + c1);
      float4 fs0 = *(const float4*)(buf + 2048 + l4 * 128 + c0);
      float4 fs1 = *(const float4*)(buf + 2048 + l4 * 128 + c1);
      uint4 af;
      af.x = pack2bf(fs0.x - fb0.x, fs0.y - fb0.y);
      af.y = pack2bf(fs0.z - fb0.z, fs0.w - fb0.w);
      af.z = pack2bf(fs1.x - fb1.x, fs1.y - fb1.y);
      af.w = pack2bf(fs1.z - fb1.z, fs1.w - fb1.w);
      #pragma unroll
      for (int t = 0; t < 4; ++t) {
        unsigned int pq[4];
        #pragma unroll
        for (int e2 = 0; e2 < 4; ++e2) {
          float wa = W[(size_t)(colf + g * 8 + e2 * 2    ) * R_DIM + t * 16 + l4];
          float wb = W[(size_t)(colf + g * 8 + e2 * 2 + 1) * R_DIM + t * 16 + l4];
          pq[e2] = pack2bf(wa, wb);
        }
        uint4 wf; wf.x = pq[0]; wf.y = pq[1]; wf.z = pq[2]; wf.w = pq[3];
        acc[t] = __builtin_amdgcn_mfma_f32_16x16x32_bf16(
            __builtin_bit_cast(bf16vec8, af),
            __builtin_bit_cast(bf16vec8, wf), acc[t], 0, 0, 0);
      }
    }
  }

  // per-wave partials -> own staging area (dead now): [16][72] f32
  {
    float* part = (float*)wbuf;
    #pragma unroll
    for (int t = 0; t < 4; ++t)
      #pragma unroll
      for (int i = 0; i < 4; ++i)
        part[(g * 4 + i) * 72 + t * 16 + l4] = acc[t][i];
  }
  __syncthreads();

  // ---------------- Reduce K-halves + per-row partition mask --------------
  {
    const int row = tid >> 3, jg = tid & 7;     // 32 rows x 8 j-groups
    const int lr  = row & 15;
    const float* pa = (const float*)(smem + ((row >> 4) * 2 + 0) * WAVESTG);
    const float* pb = (const float*)(smem + ((row >> 4) * 2 + 1) * WAVESTG);
    int4 sb = *(const int4*)(subs + (rowbase + row) * 4);
    unsigned mbits = (1u << sb.x) | (1u << sb.y) | (1u << sb.z) | (1u << sb.w);
    unsigned short v[8];
    #pragma unroll
    for (int jj = 0; jj < 8; ++jj) {
      const int j = jg * 8 + jj;
      float sum = pa[lr * 72 + j] + pb[lr * 72 + j];
      v[jj] = ((mbits >> (j >> 3)) & 1u) ? (unsigned short)f2bf_u(sum)
                                         : (unsigned short)0;
    }
    uint4 pk;
    pk.x = (unsigned)v[0] | ((unsigned)v[1] << 16);
    pk.y = (unsigned)v[2] | ((unsigned)v[3] << 16);
    pk.z = (unsigned)v[4] | ((unsigned)v[5] << 16);
    pk.w = (unsigned)v[6] | ((unsigned)v[7] << 16);
    *(uint4*)(smem + OFF_RM + row * 144 + jg * 16) = pk;   // stride 72 shorts
  }
  __syncthreads();

  // ---------------- Phase 2: out = base(global) + rm @ W^T ----------------
  uint4 a2[2][2];     // [row-tile m][k-split s]
  #pragma unroll
  for (int m = 0; m < 2; ++m)
    #pragma unroll
    for (int s = 0; s < 2; ++s)
      a2[m][s] = *(const uint4*)(smem + OFF_RM + (m * 16 + l4) * 144 +
                                 s * 64 + g * 16);
  float* cbuf = (float*)wbuf;     // [32][72] f32 = 9216 B, wave-private
  #pragma unroll 1
  for (int grp = 0; grp < 16; ++grp) {
    const int ga = (grp + off2) & 15;           // rotated column group
    const int cbase = wave * 1024 + ga * 64;
    float4 bb[8];
    #pragma unroll
    for (int v2 = 0; v2 < 8; ++v2) {
      const int r = g + v2 * 4;
      bb[v2] = *(const float4*)(base + (rowbase + r) * D_DIM + cbase + l4 * 4);
    }
    f32x4v a[2][4];
    #pragma unroll
    for (int m = 0; m < 2; ++m)
      #pragma unroll
      for (int t = 0; t < 4; ++t) a[m][t] = (f32x4v){0.f, 0.f, 0.f, 0.f};
    #pragma unroll
    for (int t = 0; t < 4; ++t) {
      #pragma unroll
      for (int s = 0; s < 2; ++s) {
        uint4 bfrag;  // B[kk=j][n=col] = W[col][j]
        if (USE_WS) {
          bfrag = *(const uint4*)(Wb_bf + (size_t)(cbase + t * 16 + l4) * R_DIM +
                                  s * 32 + g * 8);
        } else {
          const float* wp = W + (size_t)(cbase + t * 16 + l4) * R_DIM + s * 32 + g * 8;
          float4 wa = *(const float4*)(wp);
          float4 wb2 = *(const float4*)(wp + 4);
          bfrag.x = pack2bf(wa.x, wa.y); bfrag.y = pack2bf(wa.z, wa.w);
          bfrag.z = pack2bf(wb2.x, wb2.y); bfrag.w = pack2bf(wb2.z, wb2.w);
        }
        #pragma unroll
        for (int m = 0; m < 2; ++m)
          a[m][t] = __builtin_amdgcn_mfma_f32_16x16x32_bf16(
              __builtin_bit_cast(bf16vec8, a2[m][s]),
              __builtin_bit_cast(bf16vec8, bfrag), a[m][t], 0, 0, 0);
      }
    }
    #pragma unroll
    for (int m = 0; m < 2; ++m)
      #pragma unroll
      for (int t = 0; t < 4; ++t)
        #pragma unroll
        for (int i = 0; i < 4; ++i)
          cbuf[(m * 16 + g * 4 + i) * 72 + t * 16 + l4] = a[m][t][i];
    #pragma unroll
    for (int v2 = 0; v2 < 8; ++v2) {
      const int r = g + v2 * 4;
      f32x4v cv = *(const f32x4v*)(cbuf + r * 72 + l4 * 4);
      float4 o;
      o.x = cv[0] + bb[v2].x;
      o.y = cv[1] + bb[v2].y;
      o.z = cv[2] + bb[v2].z;
      o.w = cv[3] + bb[v2].w;
      *(float4*)(out + (rowbase + r) * D_DIM + cbase + l4 * 4) = o;
    }
  }
}

extern "C" void kernel_launch(void* const* d_in, const int* in_sizes, int n_in,
                              void* d_out, int out_size, void* d_ws, size_t ws_size,
                              hipStream_t stream) {
  const float* base = (const float*)d_in[0];
  const float* srcp = (const float*)d_in[1];
  const float* W    = (const float*)d_in[2];
  const int*   subs = (const int*)d_in[3];
  float* out = (float*)d_out;

  const int nblocks = 16384 / BM;   // 512 = 8 XCDs x 64 (bijective remap ok)
  const size_t wbytes = (size_t)2 * R_DIM * D_DIM * sizeof(unsigned short); // 1 MB
  if (d_ws && ws_size >= wbytes) {
    unsigned short* Wt = (unsigned short*)d_ws;          // [64][4096] bf16
    unsigned short* Wb = Wt + (size_t)R_DIM * D_DIM;     // [4096][64] bf16
    lrri_prep<<<256, 256, 0, stream>>>(W, Wt, Wb);
    lrri_fused<true><<<nblocks, 256, 0, stream>>>(base, srcp, W, subs, Wt, Wb, out);
  } else {
    lrri_fused<false><<<nblocks, 256, 0, stream>>>(base, srcp, W, subs, nullptr, nullptr, out);
  }
}